// Round 12
// baseline (101.104 us; speedup 1.0000x reference)
//
#include <hip/hip_runtime.h>

// rmsdLoss via associative affine scan — R22 (= R21 resubmit; R11 bench was
// an infra failure: "MI355X container failed twice", no kernel verdict).
// R19/R20 confirmed: time tracks per-row wave-instruction count.
// R21/22 cuts the cross-wave epilogue via rigid-motion invariance:
// sum|p_P - p_T|^2 = sum|u_k - (D v_k + d)|^2 with D = G_P^T G_T,
// d = G_P^T(gt_T - gt_P). ONE LANE OWNS BOTH CHAINS: block = 64 thr =
// 1 wave/row; lane l holds steps [16l,16l+16) of pred AND targ; two
// full-wave scans in the same wave. Diff is lane-local -> pos arena, ini
// relay, and BOTH barriers deleted; LDS -> 0. Per-row ~3740 -> ~3050
// wave-instrs (-18%); each thread has 2 independent dep chains (2x ILP).
// Clip specialization: template<bool CLIP> (reference clips pred only).
// Register plan: tlP+tlT = 96 persistent, peak ~160-200.
// amdgpu_waves_per_eu(2,2) pins 2 waves/SIMD -> 256-VGPR budget, no
// spill-chasing (R12 lesson). 2048 single-wave blocks = 8 blocks/CU.
// Predicted: dur_us 96.7 -> ~90-93 (kernel ~19 -> 13-16us). If flat/worse:
// WRITE_SIZE >> 64B -> spills -> relax pin; else occupancy loss -> revert
// to 128-thr geometry keeping the fused diff.

#define LROW  4087
#define NSTEP 1021
#define NROW  2048
#define CHUNK 16
#define EPSF  1e-6f
#define INVMEAN (1.0f / (2048.0f * 1024.0f * 3.0f))

__device__ __forceinline__ float frcp(float x){ return __builtin_amdgcn_rcpf(x); }
__device__ __forceinline__ float frsq(float x){ return __builtin_amdgcn_rsqf(x); }

// Build + compose + in-wave scans + fold for ONE chain. Returns the lane's
// global transform G (columns g0,g1,g2 + translation gt), local-prefix
// translations tl[k], and the first-atoms params (a1x, a2x, a2y).
template<bool CLIP>
__device__ __forceinline__ void chainScan(
    const float* __restrict__ v, const int ln, const int j0,
    float tl[CHUNK][3],
    float &g0x, float &g0y, float &g0z,
    float &g1x, float &g1y, float &g1z,
    float &g2x, float &g2y, float &g2z,
    float &gtx, float &gty, float &gtz,
    float &a1x, float &a2x, float &a2y)
{
  // broadcast fold inputs (wave-uniform -> scalar loads)
  float rb0 = v[3064], rd0 = v[2042], rb1 = v[3065];
  if (CLIP){
    rb0 = fminf(fmaxf(rb0, -1.f), 1.f);
    rd0 = fminf(fmaxf(rd0, -1.f), 1.f);
    rb1 = fminf(fmaxf(rb1, -1.f), 1.f);
  }

  // ---- batch per-lane loads: 65 contiguous dwords, all independent ----
  float s0[CHUNK], s1[CHUNK], dd[CHUNK], bv[CHUNK+1];
  #pragma unroll
  for (int k = 0; k < CHUNK; ++k){
    s0[k] = v[2*(j0+k)];
    s1[k] = v[2*(j0+k)+1];
    dd[k] = v[2043 + j0 + k];        // lane63 k>=13: valid mem, garbage steps unconsumed
  }
  #pragma unroll
  for (int m = 0; m <= CHUNK; ++m){
    int ix = 3065 + j0 + m;
    if (ix > 4086) ix = 4086;        // tail lane clamp (garbage bounded)
    float b = v[ix];
    if (CLIP) b = fminf(fmaxf(b, -1.f), 1.f);
    bv[m] = fmaf(b, 1.05f, 1.95f);
  }

  // ---- fused build + compose (closed-form steps), snapshot translations ----
  float c0x,c0y,c0z, c1x,c1y,c1z, c2x,c2y,c2z, tx,ty,tz;
  #pragma unroll
  for (int k = 0; k < CHUNK; ++k){
    float a0 = s0[k], a1v = s1[k], dr = dd[k];
    if (CLIP){
      a0  = fminf(fmaxf(a0,  -1.f), 1.f);
      a1v = fminf(fmaxf(a1v, -1.f), 1.f);
      dr  = fminf(fmaxf(dr,  -1.f), 1.f);
    }
    const float d  = fmaf(dr, 1.75f, 3.25f);
    const float b1 = bv[k], b2 = bv[k+1];
    float ct = (b1*b1 + b2*b2 - d*d) * frcp(2.0f*b1*b2);
    ct = fminf(fmaxf(ct, -1.0f + EPSF), 1.0f - EPSF);
    const float omc = fmaxf(1.0f - ct*ct, 1e-12f);
    const float ist = frsq(omc);           // 1/st
    const float st  = omc * ist;           // sqrt(omc)
    const float r2 = a0*a0 + a1v*a1v;
    const bool ok = r2 > 1e-36f;
    const float ir = ok ? frsq(r2) : 0.0f;
    const float scv = a0 * ir;                 // sin(chi)
    const float ccv = ok ? a1v * ir : 1.0f;    // cos(chi)
    const float hx = -ct, hy = st*ccv, hz = st*scv;   // unit step dir
    if (k == 0){
      c0x=hx;      c0y=hy;      c0z=hz;
      c1x=-st;     c1y=hx*ccv;  c1z=hx*scv;
      c2x=0.0f;    c2y=-scv;    c2z=ccv;
      tx=b2*hx;    ty=b2*hy;    tz=b2*hz;
    } else {
      const float n0x = c0x*hx + c1x*hy + c2x*hz;
      const float n0y = c0y*hx + c1y*hy + c2y*hz;
      const float n0z = c0z*hx + c1z*hy + c2z*hz;
      tx = fmaf(b2, n0x, tx); ty = fmaf(b2, n0y, ty); tz = fmaf(b2, n0z, tz);
      const float n1x = ist * fmaf(hx, n0x, -c0x);
      const float n1y = ist * fmaf(hx, n0y, -c0y);
      const float n1z = ist * fmaf(hx, n0z, -c0z);
      const float n2x = fmaf(ccv, c2x, -scv*c1x);
      const float n2y = fmaf(ccv, c2y, -scv*c1y);
      const float n2z = fmaf(ccv, c2z, -scv*c1z);
      c0x=n0x; c0y=n0y; c0z=n0z;
      c1x=n1x; c1y=n1y; c1z=n1z;
      c2x=n2x; c2y=n2y; c2z=n2z;
    }
    tl[k][0]=tx; tl[k][1]=ty; tl[k][2]=tz;
  }

  // ---- in-wave inclusive ROTATION scan (6-float state, c2 reconstructed) ----
  float r0x=c0x, r0y=c0y, r0z=c0z, r1x=c1x, r1y=c1y, r1z=c1z;
  #pragma unroll
  for (int off = 1; off < 64; off <<= 1){
    const float o0x=__shfl_up(r0x,off), o0y=__shfl_up(r0y,off), o0z=__shfl_up(r0z,off);
    const float o1x=__shfl_up(r1x,off), o1y=__shfl_up(r1y,off), o1z=__shfl_up(r1z,off);
    const float o2x = o0y*o1z - o0z*o1y;
    const float o2y = o0z*o1x - o0x*o1z;
    const float o2z = o0x*o1y - o0y*o1x;
    const float n0x = o0x*r0x + o1x*r0y + o2x*r0z;
    const float n0y = o0y*r0x + o1y*r0y + o2y*r0z;
    const float n0z = o0z*r0x + o1z*r0y + o2z*r0z;
    const float n1x = o0x*r1x + o1x*r1y + o2x*r1z;
    const float n1y = o0y*r1x + o1y*r1y + o2y*r1z;
    const float n1z = o0z*r1x + o1z*r1y + o2z*r1z;
    if (ln >= off){
      r0x=n0x; r0y=n0y; r0z=n0z;
      r1x=n1x; r1y=n1y; r1z=n1z;
    }
  }

  // exclusive rotation prefix
  float e0x=__shfl_up(r0x,1), e0y=__shfl_up(r0y,1), e0z=__shfl_up(r0z,1);
  float e1x=__shfl_up(r1x,1), e1y=__shfl_up(r1y,1), e1z=__shfl_up(r1z,1);
  if (ln == 0){ e0x=1.f; e0y=0.f; e0z=0.f; e1x=0.f; e1y=1.f; e1z=0.f; }

  // ---- translation: w = E.M * t_chunk, then commutative 3-float sum scan ----
  {
    const float x2x = e0y*e1z - e0z*e1y;
    const float x2y = e0z*e1x - e0x*e1z;
    const float x2z = e0x*e1y - e0y*e1x;
    const float wx = e0x*tx + e1x*ty + x2x*tz;
    const float wy = e0y*tx + e1y*ty + x2y*tz;
    const float wz = e0z*tx + e1z*ty + x2z*tz;
    float sx=wx, sy=wy, sz=wz;
    #pragma unroll
    for (int off = 1; off < 64; off <<= 1){
      const float ax=__shfl_up(sx,off), ay=__shfl_up(sy,off), az=__shfl_up(sz,off);
      if (ln >= off){ sx+=ax; sy+=ay; sz+=az; }
    }
    tx = sx - wx; ty = sy - wy; tz = sz - wz;   // exclusive translation prefix
  }

  // ---- fold (F0, a2): G = F0*E ; G.t = a2 + F0*E.t ----
  const float bl0 = fmaf(rb0, 1.05f, 1.95f);
  const float d0  = fmaf(rd0, 1.75f, 3.25f);
  const float b1f = fmaf(rb1, 1.05f, 1.95f);
  float ct0 = (bl0*bl0 + b1f*b1f - d0*d0) * frcp(2.0f*bl0*b1f);
  ct0 = fminf(fmaxf(ct0, -1.0f + EPSF), 1.0f - EPSF);
  const float st0 = sqrtf(fmaxf(1.0f - ct0*ct0, 0.0f));
  a1x = bl0;
  a2x = bl0 - b1f*ct0;
  a2y = b1f*st0;

  const float e2x = e0y*e1z - e0z*e1y;
  const float e2y = e0z*e1x - e0x*e1z;
  const float e2z = e0x*e1y - e0y*e1x;

  g0x = -ct0*e0x - st0*e0y; g0y = st0*e0x - ct0*e0y; g0z = e0z;
  g1x = -ct0*e1x - st0*e1y; g1y = st0*e1x - ct0*e1y; g1z = e1z;
  g2x = -ct0*e2x - st0*e2y; g2y = st0*e2x - ct0*e2y; g2z = e2z;
  gtx = a2x - ct0*tx - st0*ty;
  gty = a2y + st0*tx - ct0*ty;
  gtz = tz;
}

__global__ void __launch_bounds__(64) __attribute__((amdgpu_waves_per_eu(2, 2)))
rmsd_kernel(const float* __restrict__ pred, const float* __restrict__ targ,
            float* __restrict__ ws){
  const int row = blockIdx.x;
  const int ln  = threadIdx.x;        // 0..63, one wave
  const int j0  = ln * CHUNK;         // first step owned (<= 1008)

  const float* __restrict__ vp = pred + (size_t)row * LROW;
  const float* __restrict__ vt = targ + (size_t)row * LROW;

  float tlP[CHUNK][3], tlT[CHUNK][3];
  float P0x,P0y,P0z, P1x,P1y,P1z, P2x,P2y,P2z, Ptx,Pty,Ptz, Pa1,Pa2x,Pa2y;
  float T0x,T0y,T0z, T1x,T1y,T1z, T2x,T2y,T2z, Ttx,Tty,Ttz, Ta1,Ta2x,Ta2y;

  chainScan<true >(vp, ln, j0, tlP, P0x,P0y,P0z, P1x,P1y,P1z, P2x,P2y,P2z,
                   Ptx,Pty,Ptz, Pa1,Pa2x,Pa2y);
  chainScan<false>(vt, ln, j0, tlT, T0x,T0y,T0z, T1x,T1y,T1z, T2x,T2y,T2z,
                   Ttx,Tty,Ttz, Ta1,Ta2x,Ta2y);

  // ---- D = G_P^T G_T (columns), d = G_P^T (gt_T - gt_P) ----
  // |p_P - p_T|^2 = |u - (D v + d)|^2  (G_P orthonormal)
  const float D00 = P0x*T0x + P0y*T0y + P0z*T0z;   // col0
  const float D10 = P1x*T0x + P1y*T0y + P1z*T0z;
  const float D20 = P2x*T0x + P2y*T0y + P2z*T0z;
  const float D01 = P0x*T1x + P0y*T1y + P0z*T1z;   // col1
  const float D11 = P1x*T1x + P1y*T1y + P1z*T1z;
  const float D21 = P2x*T1x + P2y*T1y + P2z*T1z;
  const float D02 = P0x*T2x + P0y*T2y + P0z*T2z;   // col2
  const float D12 = P1x*T2x + P1y*T2y + P1z*T2z;
  const float D22 = P2x*T2x + P2y*T2y + P2z*T2z;
  const float bx = Ttx - Ptx, by = Tty - Pty, bz = Ttz - Ptz;
  const float dtx = P0x*bx + P0y*by + P0z*bz;
  const float dty = P1x*bx + P1y*by + P1z*bz;
  const float dtz = P2x*bx + P2y*by + P2z*bz;

  // ---- lane-local diff + reduce ----
  float acc = 0.0f;
  if (ln == 0){
    const float dx = Pa1  - Ta1;    // a1 differs only in x; a0 diff = 0
    const float dy = Pa2x - Ta2x;   // a2 differs in x,y (z = 0)
    const float dz = Pa2y - Ta2y;
    acc = dx*dx + dy*dy + dz*dz;
  }
  #pragma unroll
  for (int k = 0; k < CHUNK; ++k){
    if (j0 + k < NSTEP){
      const float vx = tlT[k][0], vy = tlT[k][1], vz = tlT[k][2];
      const float wx = dtx + D00*vx + D01*vy + D02*vz;
      const float wy = dty + D10*vx + D11*vy + D12*vz;
      const float wz = dtz + D20*vx + D21*vy + D22*vz;
      const float dx = tlP[k][0] - wx;
      const float dy = tlP[k][1] - wy;
      const float dz = tlP[k][2] - wz;
      acc = fmaf(dx, dx, acc);
      acc = fmaf(dy, dy, acc);
      acc = fmaf(dz, dz, acc);
    }
  }
  #pragma unroll
  for (int off = 32; off > 0; off >>= 1) acc += __shfl_down(acc, off);
  // plain store, zero contention (atomic drain was the 43us floor, R17)
  if (ln == 0) ws[row] = acc;
}

// 1 block: reduce 2048 per-row partials -> out. 8 coalesced loads/thread.
__global__ void __launch_bounds__(256, 1)
reduce_kernel(const float* __restrict__ ws, float* __restrict__ out){
  __shared__ float wsum[4];
  const int tid = threadIdx.x;
  float a = 0.0f;
  #pragma unroll
  for (int i = 0; i < 8; ++i) a += ws[tid + (i << 8)];
  #pragma unroll
  for (int off = 32; off > 0; off >>= 1) a += __shfl_down(a, off);
  if ((tid & 63) == 0) wsum[tid >> 6] = a;
  __syncthreads();
  if (tid == 0) out[0] = (wsum[0] + wsum[1] + wsum[2] + wsum[3]) * INVMEAN;
}

extern "C" void kernel_launch(void* const* d_in, const int* in_sizes, int n_in,
                              void* d_out, int out_size, void* d_ws, size_t ws_size,
                              hipStream_t stream) {
  const float* pred = (const float*)d_in[0];
  const float* targ = (const float*)d_in[1];
  float* out = (float*)d_out;
  float* ws  = (float*)d_ws;   // needs 2048 floats = 8 KB

  rmsd_kernel<<<NROW, 64, 0, stream>>>(pred, targ, ws);
  reduce_kernel<<<1, 256, 0, stream>>>(ws, out);
}